// Round 4
// baseline (1231.606 us; speedup 1.0000x reference)
//
#include <hip/hip_runtime.h>
#include <cstdint>
#include <cstddef>

#define E_DIM 512
#define H_DIM 512
#define V_DIM 32000
#define B_DIM 64
#define T_DIM 20
#define G4    2048   // 4*H

typedef _Float16 f16;
typedef _Float16 f16x8 __attribute__((ext_vector_type(8)));
typedef _Float16 f16x4 __attribute__((ext_vector_type(4)));
typedef float    f32x4 __attribute__((ext_vector_type(4)));

__device__ __forceinline__ void async_lds16(void* lds, const void* g) {
  __builtin_amdgcn_global_load_lds(
      (const __attribute__((address_space(1))) uint32_t*)g,
      (__attribute__((address_space(3))) uint32_t*)lds, 16, 0, 0);
}

__device__ __forceinline__ float sigmoidf_(float x) {
  return 1.0f / (1.0f + expf(-x));
}

// ---------------------------------------------------------------------------
// Input projection: P[m][g*512+u] = x_m . w_ih[g*512+u] + b_ih + b_hh
// m = b*21 + t;  x_m = features[b] (t==0) else emb_table[captions[b][t-1]]
// grid (128 u-chunks, 21 m-chunks) x 256 threads
// ---------------------------------------------------------------------------
__global__ __launch_bounds__(256) void proj_kernel(
    const float* __restrict__ features, const int* __restrict__ captions,
    const float* __restrict__ emb, const float* __restrict__ w_ih,
    const float* __restrict__ b_ih, const float* __restrict__ b_hh,
    float* __restrict__ P) {
  const int tid = threadIdx.x;
  const int m = blockIdx.y * 64 + (tid & 63);        // 0..1343
  const int u = blockIdx.x * 4 + (tid >> 6);         // 0..511
  const int b = m / 21;
  const int t = m % 21;
  const float* x = (t == 0) ? (features + (size_t)b * E_DIM)
                            : (emb + (size_t)captions[b * T_DIM + (t - 1)] * E_DIM);
  const float4* x4 = (const float4*)x;
  const float4* w0 = (const float4*)(w_ih + (size_t)(0 * H_DIM + u) * E_DIM);
  const float4* w1 = (const float4*)(w_ih + (size_t)(1 * H_DIM + u) * E_DIM);
  const float4* w2 = (const float4*)(w_ih + (size_t)(2 * H_DIM + u) * E_DIM);
  const float4* w3 = (const float4*)(w_ih + (size_t)(3 * H_DIM + u) * E_DIM);
  float a0 = 0.f, a1 = 0.f, a2 = 0.f, a3 = 0.f;
#pragma unroll 8
  for (int k = 0; k < E_DIM / 4; ++k) {
    const float4 xv = x4[k];
    const float4 v0 = w0[k];
    const float4 v1 = w1[k];
    const float4 v2 = w2[k];
    const float4 v3 = w3[k];
    a0 += xv.x * v0.x + xv.y * v0.y + xv.z * v0.z + xv.w * v0.w;
    a1 += xv.x * v1.x + xv.y * v1.y + xv.z * v1.z + xv.w * v1.w;
    a2 += xv.x * v2.x + xv.y * v2.y + xv.z * v2.z + xv.w * v2.w;
    a3 += xv.x * v3.x + xv.y * v3.y + xv.z * v3.z + xv.w * v3.w;
  }
  float* Pm = P + (size_t)m * G4;
  Pm[0 * H_DIM + u] = a0 + b_ih[0 * H_DIM + u] + b_hh[0 * H_DIM + u];
  Pm[1 * H_DIM + u] = a1 + b_ih[1 * H_DIM + u] + b_hh[1 * H_DIM + u];
  Pm[2 * H_DIM + u] = a2 + b_ih[2 * H_DIM + u] + b_hh[2 * H_DIM + u];
  Pm[3 * H_DIM + u] = a3 + b_ih[3 * H_DIM + u] + b_hh[3 * H_DIM + u];
}

// ---------------------------------------------------------------------------
// One LSTM step. Thread owns (b, u): computes all 4 gate dots over h_in,
// adds P, applies elementwise, writes h_out, c, and fp16 copy of h (t>=1).
// grid 128 x 256 threads. b = tid&63 (lanes), u = blk*4 + (tid>>6).
// ---------------------------------------------------------------------------
__global__ __launch_bounds__(256) void lstm_step_kernel(
    const float* __restrict__ P, const float* __restrict__ w_hh,
    const float* __restrict__ h_in, float* __restrict__ h_out,
    float* __restrict__ c, f16* __restrict__ hs16, int t) {
  const int tid = threadIdx.x;
  const int b = tid & 63;
  const int u = blockIdx.x * 4 + (tid >> 6);
  const float4* h4 = (const float4*)(h_in + (size_t)b * H_DIM);
  const float4* w0 = (const float4*)(w_hh + (size_t)(0 * H_DIM + u) * H_DIM);
  const float4* w1 = (const float4*)(w_hh + (size_t)(1 * H_DIM + u) * H_DIM);
  const float4* w2 = (const float4*)(w_hh + (size_t)(2 * H_DIM + u) * H_DIM);
  const float4* w3 = (const float4*)(w_hh + (size_t)(3 * H_DIM + u) * H_DIM);
  float a0 = 0.f, a1 = 0.f, a2 = 0.f, a3 = 0.f;
#pragma unroll 8
  for (int k = 0; k < H_DIM / 4; ++k) {
    const float4 hv = h4[k];
    const float4 v0 = w0[k];
    const float4 v1 = w1[k];
    const float4 v2 = w2[k];
    const float4 v3 = w3[k];
    a0 += hv.x * v0.x + hv.y * v0.y + hv.z * v0.z + hv.w * v0.w;
    a1 += hv.x * v1.x + hv.y * v1.y + hv.z * v1.z + hv.w * v1.w;
    a2 += hv.x * v2.x + hv.y * v2.y + hv.z * v2.z + hv.w * v2.w;
    a3 += hv.x * v3.x + hv.y * v3.y + hv.z * v3.z + hv.w * v3.w;
  }
  const float* Pm = P + ((size_t)b * 21 + t) * G4;
  const float gi = a0 + Pm[0 * H_DIM + u];
  const float gf = a1 + Pm[1 * H_DIM + u];
  const float gg = a2 + Pm[2 * H_DIM + u];
  const float go = a3 + Pm[3 * H_DIM + u];
  const float si = sigmoidf_(gi);
  const float sf = sigmoidf_(gf);
  const float so = sigmoidf_(go);
  const float tg = tanhf(gg);
  const size_t bu = (size_t)b * H_DIM + u;
  const float cn = sf * c[bu] + si * tg;
  c[bu] = cn;
  const float hn = so * tanhf(cn);
  h_out[bu] = hn;
  if (t >= 1) {
    hs16[((size_t)b * T_DIM + (t - 1)) * H_DIM + u] = (f16)hn;
  }
}

// ---------------------------------------------------------------------------
// fc_w f32 -> f16   (V*H = 16.384M elems, 4 per thread)
// ---------------------------------------------------------------------------
__global__ __launch_bounds__(256) void convert_w_kernel(
    const float* __restrict__ w, f16* __restrict__ w16) {
  const int i = blockIdx.x * 256 + threadIdx.x;   // float4 index, < 4,096,000
  const float4 v = ((const float4*)w)[i];
  f16x4 r;
  r.x = (f16)v.x; r.y = (f16)v.y; r.z = (f16)v.z; r.w = (f16)v.w;
  ((f16x4*)w16)[i] = r;
}

// ---------------------------------------------------------------------------
// FC GEMM: C[m][n] = sum_k A[m][k]*Bw[n][k] + bias[n]
// A fp16 [1280][512], Bw fp16 [32000][512], C f32 [1280][32000]
// 128x128 tile, BK=64, 4 waves (2x2), 16x16x32 f16 MFMA, global_load_lds.
// grid (250 n-tiles, 10 m-tiles) x 256 threads
// ---------------------------------------------------------------------------
__global__ __launch_bounds__(256) void fc_gemm_kernel(
    const f16* __restrict__ A, const f16* __restrict__ Bw,
    const float* __restrict__ bias, float* __restrict__ C) {
  __shared__ f16 As[128 * 64];
  __shared__ f16 Bs[128 * 64];
  const int tid = threadIdx.x;
  const int lane = tid & 63;
  const int wid = tid >> 6;
  const int m0 = blockIdx.y * 128;
  const int n0 = blockIdx.x * 128;
  const int wm = (wid >> 1) * 64;
  const int wn = (wid & 1) * 64;

  f32x4 acc[4][4];
#pragma unroll
  for (int i = 0; i < 4; ++i)
#pragma unroll
    for (int j = 0; j < 4; ++j) {
      f32x4 z = {0.f, 0.f, 0.f, 0.f};
      acc[i][j] = z;
    }

  const int lr = lane & 15;
  const int lkb = (lane >> 4) * 8;

  for (int kt = 0; kt < 512; kt += 64) {
    // stage 16KB A-tile + 16KB B-tile; per issue: wave-uniform LDS base,
    // HW writes base + lane*16; per-lane global src matches that slot.
#pragma unroll
    for (int i = 0; i < 4; ++i) {
      const int off = i * 4096 + wid * 1024 + lane * 16;  // byte off in tile
      const int row = off >> 7;                           // /128B per row
      const int colh = (off & 127) >> 1;                  // fp16 col
      async_lds16((char*)As + i * 4096 + wid * 1024,
                  A + (size_t)(m0 + row) * 512 + kt + colh);
      async_lds16((char*)Bs + i * 4096 + wid * 1024,
                  Bw + (size_t)(n0 + row) * 512 + kt + colh);
    }
    __syncthreads();
#pragma unroll
    for (int ks = 0; ks < 2; ++ks) {
      f16x8 af[4], bf[4];
#pragma unroll
      for (int mi = 0; mi < 4; ++mi)
        af[mi] = *(const f16x8*)&As[(wm + mi * 16 + lr) * 64 + ks * 32 + lkb];
#pragma unroll
      for (int ni = 0; ni < 4; ++ni)
        bf[ni] = *(const f16x8*)&Bs[(wn + ni * 16 + lr) * 64 + ks * 32 + lkb];
#pragma unroll
      for (int mi = 0; mi < 4; ++mi)
#pragma unroll
        for (int ni = 0; ni < 4; ++ni)
          acc[mi][ni] = __builtin_amdgcn_mfma_f32_16x16x32_f16(
              af[mi], bf[ni], acc[mi][ni], 0, 0, 0);
    }
    __syncthreads();
  }

#pragma unroll
  for (int mi = 0; mi < 4; ++mi) {
    const int mbase = m0 + wm + mi * 16 + (lane >> 4) * 4;
#pragma unroll
    for (int ni = 0; ni < 4; ++ni) {
      const int n = n0 + wn + ni * 16 + lr;
      const float bv = bias[n];
#pragma unroll
      for (int r = 0; r < 4; ++r)
        C[(size_t)(mbase + r) * V_DIM + n] = acc[mi][ni][r] + bv;
    }
  }
}

// ---------------------------------------------------------------------------
// In-place row softmax over V=32000. One block per row, 256 threads.
// 3 passes: max, sum(exp), normalize. float4 everywhere (32000/4 = 8000).
// ---------------------------------------------------------------------------
__device__ __forceinline__ float waveMax(float v) {
#pragma unroll
  for (int o = 32; o > 0; o >>= 1) v = fmaxf(v, __shfl_down(v, o));
  return v;
}
__device__ __forceinline__ float waveSum(float v) {
#pragma unroll
  for (int o = 32; o > 0; o >>= 1) v += __shfl_down(v, o);
  return v;
}

__global__ __launch_bounds__(256) void softmax_kernel(float* __restrict__ out) {
  float* p = out + (size_t)blockIdx.x * V_DIM;
  float4* p4 = (float4*)p;
  const int t = threadIdx.x;
  __shared__ float sred[4];

  // pass 1: max
  float m = -1e30f;
  for (int i = t; i < 8000; i += 256) {
    const float4 v = p4[i];
    m = fmaxf(m, fmaxf(fmaxf(v.x, v.y), fmaxf(v.z, v.w)));
  }
  m = waveMax(m);
  if ((t & 63) == 0) sred[t >> 6] = m;
  __syncthreads();
  m = fmaxf(fmaxf(sred[0], sred[1]), fmaxf(sred[2], sred[3]));
  __syncthreads();

  // pass 2: sum of exp
  float s = 0.f;
  for (int i = t; i < 8000; i += 256) {
    const float4 v = p4[i];
    s += expf(v.x - m) + expf(v.y - m) + expf(v.z - m) + expf(v.w - m);
  }
  s = waveSum(s);
  if ((t & 63) == 0) sred[t >> 6] = s;
  __syncthreads();
  const float inv = 1.0f / (sred[0] + sred[1] + sred[2] + sred[3]);

  // pass 3: write
  for (int i = t; i < 8000; i += 256) {
    float4 v = p4[i];
    v.x = expf(v.x - m) * inv;
    v.y = expf(v.y - m) * inv;
    v.z = expf(v.z - m) * inv;
    v.w = expf(v.w - m) * inv;
    p4[i] = v;
  }
}

// ---------------------------------------------------------------------------
extern "C" void kernel_launch(void* const* d_in, const int* in_sizes, int n_in,
                              void* d_out, int out_size, void* d_ws, size_t ws_size,
                              hipStream_t stream) {
  const float* features = (const float*)d_in[0];
  const int*   captions = (const int*)d_in[1];
  // d_in[2] = lenghts (unused by the reference)
  const float* emb      = (const float*)d_in[3];
  const float* w_ih     = (const float*)d_in[4];
  const float* w_hh     = (const float*)d_in[5];
  const float* b_ih     = (const float*)d_in[6];
  const float* b_hh     = (const float*)d_in[7];
  const float* fc_w     = (const float*)d_in[8];
  const float* fc_b     = (const float*)d_in[9];
  float* out = (float*)d_out;

  char* ws = (char*)d_ws;
  float* h0  = (float*)ws;  ws += (size_t)B_DIM * H_DIM * 4;          // 128 KB
  float* h1  = (float*)ws;  ws += (size_t)B_DIM * H_DIM * 4;          // 128 KB
  float* c   = (float*)ws;  ws += (size_t)B_DIM * H_DIM * 4;          // 128 KB
  f16*  hs16 = (f16*)ws;    ws += (size_t)B_DIM * T_DIM * H_DIM * 2;  // 1.25 MB
  f16*  w16  = (f16*)ws;    ws += (size_t)V_DIM * H_DIM * 2;          // 31.25 MB

  // P [1344][2048] f32 lives in d_out's first 11 MB; it is fully consumed by
  // the last lstm_step before fc_gemm starts overwriting d_out. Stream-ordered.
  float* P = out;

  hipMemsetAsync(h0, 0, (size_t)B_DIM * H_DIM * 4, stream);
  hipMemsetAsync(c,  0, (size_t)B_DIM * H_DIM * 4, stream);

  proj_kernel<<<dim3(128, 21), 256, 0, stream>>>(features, captions, emb, w_ih,
                                                 b_ih, b_hh, P);
  convert_w_kernel<<<16000, 256, 0, stream>>>(fc_w, w16);

  float* hb[2] = {h0, h1};
  for (int t = 0; t <= T_DIM; ++t) {
    lstm_step_kernel<<<128, 256, 0, stream>>>(P, w_hh, hb[t & 1], hb[(t + 1) & 1],
                                              c, hs16, t);
  }

  fc_gemm_kernel<<<dim3(250, 10), 256, 0, stream>>>(hs16, w16, fc_b, out);
  softmax_kernel<<<1280, 256, 0, stream>>>(out);
}

// Round 5
// 455.963 us; speedup vs baseline: 2.7011x; 2.7011x over previous
//
#include <hip/hip_runtime.h>
#include <cstdint>
#include <cstddef>

#define E_DIM 512
#define H_DIM 512
#define V_DIM 32000
#define B_DIM 64
#define T_DIM 20

typedef _Float16 f16;
typedef _Float16 f16x8 __attribute__((ext_vector_type(8)));
typedef _Float16 f16x4 __attribute__((ext_vector_type(4)));
typedef float    f32x4 __attribute__((ext_vector_type(4)));

__device__ __forceinline__ void async_lds16(void* lds, const void* g) {
  __builtin_amdgcn_global_load_lds(
      (const __attribute__((address_space(1))) uint32_t*)g,
      (__attribute__((address_space(3))) uint32_t*)lds, 16, 0, 0);
}

__device__ __forceinline__ float sigmoidf_(float x) {
  return 1.0f / (1.0f + expf(-x));
}

// ---------------------------------------------------------------------------
// Gather x rows to fp16: x16[m][512], m = b*21+t; rows 1344..1407 zero pad.
// grid 1408 x 128 threads (thread j -> cols 4j..4j+3)
// ---------------------------------------------------------------------------
__global__ __launch_bounds__(128) void gather_x16_kernel(
    const float* __restrict__ features, const int* __restrict__ captions,
    const float* __restrict__ emb, f16* __restrict__ x16) {
  const int m = blockIdx.x;
  const int j = threadIdx.x;
  f16x4 r4 = {(f16)0.f, (f16)0.f, (f16)0.f, (f16)0.f};
  if (m < 1344) {
    const int b = m / 21;
    const int t = m % 21;
    const float* src = (t == 0)
        ? features + (size_t)b * E_DIM
        : emb + (size_t)captions[b * T_DIM + (t - 1)] * E_DIM;
    const float4 v = ((const float4*)src)[j];
    r4.x = (f16)v.x; r4.y = (f16)v.y; r4.z = (f16)v.z; r4.w = (f16)v.w;
  }
  ((f16x4*)(x16 + (size_t)m * 512))[j] = r4;
}

// ---------------------------------------------------------------------------
// f32 -> f16 flat convert, 4 elems/thread; grid chosen exactly (no bounds).
// ---------------------------------------------------------------------------
__global__ __launch_bounds__(256) void convert_w_kernel(
    const float* __restrict__ w, f16* __restrict__ w16) {
  const int i = blockIdx.x * 256 + threadIdx.x;
  const float4 v = ((const float4*)w)[i];
  f16x4 r;
  r.x = (f16)v.x; r.y = (f16)v.y; r.z = (f16)v.z; r.w = (f16)v.w;
  ((f16x4*)w16)[i] = r;
}

// bsum = b_ih + b_hh (2048)
__global__ __launch_bounds__(256) void bias_sum_kernel(
    const float* __restrict__ a, const float* __restrict__ b,
    float* __restrict__ o) {
  const int i = blockIdx.x * 256 + threadIdx.x;
  if (i < 2048) o[i] = a[i] + b[i];
}

// ---------------------------------------------------------------------------
// Generic K=512 fp16 GEMM (B^T form): C[m][n] = A[m][:].Bw[n][:] + bias[n]
// 128x128 tile, BK=64, 4 waves (2x2), 16x16x32 f16 MFMA, global_load_lds.
// grid (N/128, M/128) x 256. Used for proj (ldc=2048) and fc (ldc=32000).
// ---------------------------------------------------------------------------
__global__ __launch_bounds__(256) void gemm16_kernel(
    const f16* __restrict__ A, const f16* __restrict__ Bw,
    const float* __restrict__ bias, float* __restrict__ C, int ldc) {
  __shared__ f16 As[128 * 64];
  __shared__ f16 Bs[128 * 64];
  const int tid = threadIdx.x;
  const int lane = tid & 63;
  const int wid = tid >> 6;
  const int m0 = blockIdx.y * 128;
  const int n0 = blockIdx.x * 128;
  const int wm = (wid >> 1) * 64;
  const int wn = (wid & 1) * 64;

  f32x4 acc[4][4];
#pragma unroll
  for (int i = 0; i < 4; ++i)
#pragma unroll
    for (int j = 0; j < 4; ++j) {
      f32x4 z = {0.f, 0.f, 0.f, 0.f};
      acc[i][j] = z;
    }

  const int lr = lane & 15;
  const int lkb = (lane >> 4) * 8;

  for (int kt = 0; kt < 512; kt += 64) {
#pragma unroll
    for (int i = 0; i < 4; ++i) {
      const int off = i * 4096 + wid * 1024 + lane * 16;  // byte off in tile
      const int row = off >> 7;
      const int colh = (off & 127) >> 1;
      async_lds16((char*)As + i * 4096 + wid * 1024,
                  A + (size_t)(m0 + row) * 512 + kt + colh);
      async_lds16((char*)Bs + i * 4096 + wid * 1024,
                  Bw + (size_t)(n0 + row) * 512 + kt + colh);
    }
    __syncthreads();
#pragma unroll
    for (int ks = 0; ks < 2; ++ks) {
      f16x8 af[4], bf[4];
#pragma unroll
      for (int mi = 0; mi < 4; ++mi)
        af[mi] = *(const f16x8*)&As[(wm + mi * 16 + lr) * 64 + ks * 32 + lkb];
#pragma unroll
      for (int ni = 0; ni < 4; ++ni)
        bf[ni] = *(const f16x8*)&Bs[(wn + ni * 16 + lr) * 64 + ks * 32 + lkb];
#pragma unroll
      for (int mi = 0; mi < 4; ++mi)
#pragma unroll
        for (int ni = 0; ni < 4; ++ni)
          acc[mi][ni] = __builtin_amdgcn_mfma_f32_16x16x32_f16(
              af[mi], bf[ni], acc[mi][ni], 0, 0, 0);
    }
    __syncthreads();
  }

#pragma unroll
  for (int mi = 0; mi < 4; ++mi) {
    const int mbase = m0 + wm + mi * 16 + (lane >> 4) * 4;
#pragma unroll
    for (int ni = 0; ni < 4; ++ni) {
      const int n = n0 + wn + ni * 16 + lr;
      const float bv = bias[n];
#pragma unroll
      for (int r = 0; r < 4; ++r)
        C[(size_t)(mbase + r) * ldc + n] = acc[mi][ni][r] + bv;
    }
  }
}

// ---------------------------------------------------------------------------
// One LSTM step via MFMA. grid 128 blocks (block owns 4 h-units), 256 thr.
// gates[64b][16 gate-rows] = h16[64][512] @ Whh16_slice^T + P.
// LDS: hS[64][520] f16 (padded rows -> <=4-way bank aliasing), wS[16][520].
// wS row rr = g*4+j  <->  Whh row g*512 + u0 + j   (PyTorch gate order).
// C/D frag: b = wave*16 + (lane>>4)*4 + r ; gate-row = lane&15.
// Gates i,f,g,o live at lanes fr, fr^4, fr^8, fr^12 -> shfl_xor gather.
// ---------------------------------------------------------------------------
__global__ __launch_bounds__(256) void lstm_mfma_step(
    const float* __restrict__ P, const f16* __restrict__ Whh,
    const f16* __restrict__ h_in, f16* __restrict__ h_out,
    float* __restrict__ c, f16* __restrict__ hs16, int t) {
  __shared__ f16 hS[64 * 520];
  __shared__ f16 wS[16 * 520];
  const int tid = threadIdx.x;
  const int lane = tid & 63;
  const int w = tid >> 6;            // wave id = m-tile (16 b-rows)
  const int u0 = blockIdx.x * 4;     // 4 h-units

  // stage h: 64 rows x 512 f16, coalesced f16x8
  for (int i = tid; i < 4096; i += 256) {
    const int r = i >> 6;
    const int cc = (i & 63) * 8;
    *(f16x8*)&hS[r * 520 + cc] = *(const f16x8*)&h_in[(size_t)r * 512 + cc];
  }
  // stage w: 16 rows (4 gates x 4 units)
  for (int i = tid; i < 1024; i += 256) {
    const int rr = i >> 6;
    const int cc = (i & 63) * 8;
    const int g = rr >> 2, j = rr & 3;
    *(f16x8*)&wS[rr * 520 + cc] =
        *(const f16x8*)&Whh[((size_t)(g * 512 + u0 + j)) * 512 + cc];
  }
  __syncthreads();

  const int fr = lane & 15;
  const int fq = lane >> 4;
  f32x4 acc = {0.f, 0.f, 0.f, 0.f};
#pragma unroll
  for (int kk = 0; kk < 16; ++kk) {
    const int kc = kk * 32 + fq * 8;
    const f16x8 a = *(const f16x8*)&hS[(w * 16 + fr) * 520 + kc];
    const f16x8 b = *(const f16x8*)&wS[fr * 520 + kc];
    acc = __builtin_amdgcn_mfma_f32_16x16x32_f16(a, b, acc, 0, 0, 0);
  }

  // add P (pre-activation bias+input projection), P row m = b*21 + t
  const int gg = fr >> 2, jj = fr & 3;
  const int grow = gg * 512 + u0 + jj;
#pragma unroll
  for (int r = 0; r < 4; ++r) {
    const int b = w * 16 + fq * 4 + r;
    acc[r] += P[((size_t)b * 21 + t) * 2048 + grow];
  }

  // gather 4 gates to lanes with fr<4 and apply elementwise
#pragma unroll
  for (int r = 0; r < 4; ++r) {
    const float x  = acc[r];
    const float xf = __shfl_xor(x, 4);
    const float xg = __shfl_xor(x, 8);
    const float xo = __shfl_xor(x, 12);
    if (fr < 4) {
      const int b = w * 16 + fq * 4 + r;
      const int u = u0 + fr;
      const size_t bu = (size_t)b * 512 + u;
      const float si = sigmoidf_(x);
      const float sf = sigmoidf_(xf);
      const float tg = tanhf(xg);
      const float so = sigmoidf_(xo);
      const float cn = sf * c[bu] + si * tg;
      c[bu] = cn;
      const float hn = so * tanhf(cn);
      h_out[bu] = (f16)hn;
      if (t >= 1)
        hs16[((size_t)b * T_DIM + (t - 1)) * 512 + u] = (f16)hn;
    }
  }
}

// ---------------------------------------------------------------------------
// Row softmax over V=32000, row staged in LDS (125KB) -> single global read
// + single global write. One block per row, 256 threads.
// ---------------------------------------------------------------------------
__device__ __forceinline__ float waveMax(float v) {
#pragma unroll
  for (int o = 32; o > 0; o >>= 1) v = fmaxf(v, __shfl_down(v, o));
  return v;
}
__device__ __forceinline__ float waveSum(float v) {
#pragma unroll
  for (int o = 32; o > 0; o >>= 1) v += __shfl_down(v, o);
  return v;
}

__global__ __launch_bounds__(256) void softmax_kernel(float* __restrict__ out) {
  __shared__ float rowS[32000];
  __shared__ float sred[4];
  float* p = out + (size_t)blockIdx.x * V_DIM;
  float4* p4 = (float4*)p;
  float4* r4 = (float4*)rowS;
  const int t = threadIdx.x;

  // pass 1: global read -> LDS, running max
  float m = -1e30f;
  for (int i = t; i < 8000; i += 256) {
    const float4 v = p4[i];
    r4[i] = v;
    m = fmaxf(m, fmaxf(fmaxf(v.x, v.y), fmaxf(v.z, v.w)));
  }
  m = waveMax(m);
  if ((t & 63) == 0) sred[t >> 6] = m;
  __syncthreads();
  m = fmaxf(fmaxf(sred[0], sred[1]), fmaxf(sred[2], sred[3]));
  __syncthreads();

  // pass 2: sum of exp from LDS
  float s = 0.f;
  for (int i = t; i < 8000; i += 256) {
    const float4 v = r4[i];
    s += expf(v.x - m) + expf(v.y - m) + expf(v.z - m) + expf(v.w - m);
  }
  s = waveSum(s);
  if ((t & 63) == 0) sred[t >> 6] = s;
  __syncthreads();
  const float inv = 1.0f / (sred[0] + sred[1] + sred[2] + sred[3]);

  // pass 3: LDS -> global write
  for (int i = t; i < 8000; i += 256) {
    float4 v = r4[i];
    v.x = expf(v.x - m) * inv;
    v.y = expf(v.y - m) * inv;
    v.z = expf(v.z - m) * inv;
    v.w = expf(v.w - m) * inv;
    p4[i] = v;
  }
}

// ---------------------------------------------------------------------------
extern "C" void kernel_launch(void* const* d_in, const int* in_sizes, int n_in,
                              void* d_out, int out_size, void* d_ws, size_t ws_size,
                              hipStream_t stream) {
  const float* features = (const float*)d_in[0];
  const int*   captions = (const int*)d_in[1];
  // d_in[2] = lenghts (unused by the reference)
  const float* emb      = (const float*)d_in[3];
  const float* w_ih     = (const float*)d_in[4];
  const float* w_hh     = (const float*)d_in[5];
  const float* b_ih     = (const float*)d_in[6];
  const float* b_hh     = (const float*)d_in[7];
  const float* fc_w     = (const float*)d_in[8];
  const float* fc_b     = (const float*)d_in[9];
  float* out = (float*)d_out;

  // ---- persistent-ish scratch in d_ws (proven budget <= 32.9MB) ----
  char* ws = (char*)d_ws;
  float* c    = (float*)ws; ws += (size_t)B_DIM * H_DIM * 4;            // 128 KB
  f16*   hs16 = (f16*)ws;  ws += (size_t)B_DIM * T_DIM * H_DIM * 2;     // 1.25 MB
  f16*   w16  = (f16*)ws;  ws += (size_t)V_DIM * H_DIM * 2;             // 31.25 MB

  // ---- transient scratch carved from d_out (all dead before fc_gemm) ----
  // float offsets; every region 16B-aligned, all <= 19.3MB < 163.8MB.
  float* P     = out;                          // [1408][2048] f32, 11.5 MB
  f16*   x16   = (f16*)(out + 3000000);        // [1408][512] f16, 1.44 MB
  f16*   wih16 = (f16*)(out + 3400000);        // [2048][512] f16, 2 MB
  f16*   whh16 = (f16*)(out + 4000000);        // [2048][512] f16, 2 MB
  float* bsum  = out + 4600000;                // [2048] f32
  f16*   h16a  = (f16*)(out + 4700000);        // [64][512] f16, 64 KB
  f16*   h16b  = (f16*)(out + 4800000);        // [64][512] f16, 64 KB

  hipMemsetAsync(c,    0, (size_t)B_DIM * H_DIM * 4, stream);
  hipMemsetAsync(h16a, 0, (size_t)B_DIM * H_DIM * 2, stream);

  gather_x16_kernel<<<1408, 128, 0, stream>>>(features, captions, emb, x16);
  convert_w_kernel<<<1024, 256, 0, stream>>>(w_ih, wih16);    // 2048*512
  convert_w_kernel<<<1024, 256, 0, stream>>>(w_hh, whh16);    // 2048*512
  convert_w_kernel<<<16000, 256, 0, stream>>>(fc_w, w16);     // 32000*512
  bias_sum_kernel<<<8, 256, 0, stream>>>(b_ih, b_hh, bsum);

  // proj: P[1408][2048] = x16 @ wih16^T + bsum
  gemm16_kernel<<<dim3(16, 11), 256, 0, stream>>>(x16, wih16, bsum, P, 2048);

  f16* hb[2] = {h16a, h16b};
  for (int t = 0; t <= T_DIM; ++t) {
    lstm_mfma_step<<<128, 256, 0, stream>>>(P, whh16, hb[t & 1],
                                            hb[(t + 1) & 1], c, hs16, t);
  }

  // fc: out[1280][32000] = hs16 @ w16^T + fc_b
  gemm16_kernel<<<dim3(250, 10), 256, 0, stream>>>(hs16, w16, fc_b, out, 32000);
  softmax_kernel<<<1280, 256, 0, stream>>>(out);
}

// Round 6
// 413.523 us; speedup vs baseline: 2.9783x; 1.1026x over previous
//
#include <hip/hip_runtime.h>
#include <cstdint>
#include <cstddef>

#define E_DIM 512
#define H_DIM 512
#define V_DIM 32000
#define B_DIM 64
#define T_DIM 20

typedef _Float16 f16;
typedef _Float16 f16x8 __attribute__((ext_vector_type(8)));
typedef _Float16 f16x4 __attribute__((ext_vector_type(4)));
typedef float    f32x4 __attribute__((ext_vector_type(4)));

__device__ __forceinline__ void async_lds16(void* lds, const void* g) {
  __builtin_amdgcn_global_load_lds(
      (const __attribute__((address_space(1))) uint32_t*)g,
      (__attribute__((address_space(3))) uint32_t*)lds, 16, 0, 0);
}

__device__ __forceinline__ float sigmoidf_(float x) {
  return 1.0f / (1.0f + expf(-x));
}

// ---------------------------------------------------------------------------
// Gather x rows to fp16: x16[m][512], m = b*21+t; rows 1344..1407 zero pad.
// grid 1408 x 128 threads (thread j -> cols 4j..4j+3)
// ---------------------------------------------------------------------------
__global__ __launch_bounds__(128) void gather_x16_kernel(
    const float* __restrict__ features, const int* __restrict__ captions,
    const float* __restrict__ emb, f16* __restrict__ x16) {
  const int m = blockIdx.x;
  const int j = threadIdx.x;
  f16x4 r4 = {(f16)0.f, (f16)0.f, (f16)0.f, (f16)0.f};
  if (m < 1344) {
    const int b = m / 21;
    const int t = m % 21;
    const float* src = (t == 0)
        ? features + (size_t)b * E_DIM
        : emb + (size_t)captions[b * T_DIM + (t - 1)] * E_DIM;
    const float4 v = ((const float4*)src)[j];
    r4.x = (f16)v.x; r4.y = (f16)v.y; r4.z = (f16)v.z; r4.w = (f16)v.w;
  }
  ((f16x4*)(x16 + (size_t)m * 512))[j] = r4;
}

// ---------------------------------------------------------------------------
// f32 -> f16 flat convert, 4 elems/thread; grid chosen exactly (no bounds).
// ---------------------------------------------------------------------------
__global__ __launch_bounds__(256) void convert_w_kernel(
    const float* __restrict__ w, f16* __restrict__ w16) {
  const int i = blockIdx.x * 256 + threadIdx.x;
  const float4 v = ((const float4*)w)[i];
  f16x4 r;
  r.x = (f16)v.x; r.y = (f16)v.y; r.z = (f16)v.z; r.w = (f16)v.w;
  ((f16x4*)w16)[i] = r;
}

// bsum = b_ih + b_hh (2048)
__global__ __launch_bounds__(256) void bias_sum_kernel(
    const float* __restrict__ a, const float* __restrict__ b,
    float* __restrict__ o) {
  const int i = blockIdx.x * 256 + threadIdx.x;
  if (i < 2048) o[i] = a[i] + b[i];
}

// ---------------------------------------------------------------------------
// Generic K=512 fp16 GEMM (B^T form): C[m][n] = A[m][:].Bw[n][:] + bias[n]
// 128x128 tile, BK=64, 4 waves (2x2), 16x16x32 f16 MFMA, global_load_lds.
// grid (N/128, M/128) x 256. Used for proj (ldc=2048) and fc (ldc=32000).
// ---------------------------------------------------------------------------
__global__ __launch_bounds__(256) void gemm16_kernel(
    const f16* __restrict__ A, const f16* __restrict__ Bw,
    const float* __restrict__ bias, float* __restrict__ C, int ldc) {
  __shared__ f16 As[128 * 64];
  __shared__ f16 Bs[128 * 64];
  const int tid = threadIdx.x;
  const int lane = tid & 63;
  const int wid = tid >> 6;
  const int m0 = blockIdx.y * 128;
  const int n0 = blockIdx.x * 128;
  const int wm = (wid >> 1) * 64;
  const int wn = (wid & 1) * 64;

  f32x4 acc[4][4];
#pragma unroll
  for (int i = 0; i < 4; ++i)
#pragma unroll
    for (int j = 0; j < 4; ++j) {
      f32x4 z = {0.f, 0.f, 0.f, 0.f};
      acc[i][j] = z;
    }

  const int lr = lane & 15;
  const int lkb = (lane >> 4) * 8;

  for (int kt = 0; kt < 512; kt += 64) {
#pragma unroll
    for (int i = 0; i < 4; ++i) {
      const int off = i * 4096 + wid * 1024 + lane * 16;  // byte off in tile
      const int row = off >> 7;
      const int colh = (off & 127) >> 1;
      async_lds16((char*)As + i * 4096 + wid * 1024,
                  A + (size_t)(m0 + row) * 512 + kt + colh);
      async_lds16((char*)Bs + i * 4096 + wid * 1024,
                  Bw + (size_t)(n0 + row) * 512 + kt + colh);
    }
    __syncthreads();
#pragma unroll
    for (int ks = 0; ks < 2; ++ks) {
      f16x8 af[4], bf[4];
#pragma unroll
      for (int mi = 0; mi < 4; ++mi)
        af[mi] = *(const f16x8*)&As[(wm + mi * 16 + lr) * 64 + ks * 32 + lkb];
#pragma unroll
      for (int ni = 0; ni < 4; ++ni)
        bf[ni] = *(const f16x8*)&Bs[(wn + ni * 16 + lr) * 64 + ks * 32 + lkb];
#pragma unroll
      for (int mi = 0; mi < 4; ++mi)
#pragma unroll
        for (int ni = 0; ni < 4; ++ni)
          acc[mi][ni] = __builtin_amdgcn_mfma_f32_16x16x32_f16(
              af[mi], bf[ni], acc[mi][ni], 0, 0, 0);
    }
    __syncthreads();
  }

#pragma unroll
  for (int mi = 0; mi < 4; ++mi) {
    const int mbase = m0 + wm + mi * 16 + (lane >> 4) * 4;
#pragma unroll
    for (int ni = 0; ni < 4; ++ni) {
      const int n = n0 + wn + ni * 16 + lr;
      const float bv = bias[n];
#pragma unroll
      for (int r = 0; r < 4; ++r)
        C[(size_t)(mbase + r) * ldc + n] = acc[mi][ni][r] + bv;
    }
  }
}

// ---------------------------------------------------------------------------
// One LSTM step via MFMA. grid 128 blocks (block owns 4 h-units), 256 thr.
// gates[64b][16 gate-rows] = h16[64][512] @ Whh16_slice^T + P.
// LDS: hS[64][520] f16 (padded rows -> <=4-way bank aliasing), wS[16][520].
// wS row rr = g*4+j  <->  Whh row g*512 + u0 + j   (PyTorch gate order).
// C/D frag: b = wave*16 + (lane>>4)*4 + r ; gate-row = lane&15.
// Gates i,f,g,o live at lanes fr, fr^4, fr^8, fr^12 -> shfl_xor gather.
// ---------------------------------------------------------------------------
__global__ __launch_bounds__(256) void lstm_mfma_step(
    const float* __restrict__ P, const f16* __restrict__ Whh,
    const f16* __restrict__ h_in, f16* __restrict__ h_out,
    float* __restrict__ c, f16* __restrict__ hs16, int t) {
  __shared__ f16 hS[64 * 520];
  __shared__ f16 wS[16 * 520];
  const int tid = threadIdx.x;
  const int lane = tid & 63;
  const int w = tid >> 6;            // wave id = m-tile (16 b-rows)
  const int u0 = blockIdx.x * 4;     // 4 h-units

  // stage h: 64 rows x 512 f16, coalesced f16x8
  for (int i = tid; i < 4096; i += 256) {
    const int r = i >> 6;
    const int cc = (i & 63) * 8;
    *(f16x8*)&hS[r * 520 + cc] = *(const f16x8*)&h_in[(size_t)r * 512 + cc];
  }
  // stage w: 16 rows (4 gates x 4 units)
  for (int i = tid; i < 1024; i += 256) {
    const int rr = i >> 6;
    const int cc = (i & 63) * 8;
    const int g = rr >> 2, j = rr & 3;
    *(f16x8*)&wS[rr * 520 + cc] =
        *(const f16x8*)&Whh[((size_t)(g * 512 + u0 + j)) * 512 + cc];
  }
  __syncthreads();

  const int fr = lane & 15;
  const int fq = lane >> 4;
  f32x4 acc = {0.f, 0.f, 0.f, 0.f};
#pragma unroll
  for (int kk = 0; kk < 16; ++kk) {
    const int kc = kk * 32 + fq * 8;
    const f16x8 a = *(const f16x8*)&hS[(w * 16 + fr) * 520 + kc];
    const f16x8 b = *(const f16x8*)&wS[fr * 520 + kc];
    acc = __builtin_amdgcn_mfma_f32_16x16x32_f16(a, b, acc, 0, 0, 0);
  }

  // add P (pre-activation bias+input projection), P row m = b*21 + t
  const int gg = fr >> 2, jj = fr & 3;
  const int grow = gg * 512 + u0 + jj;
#pragma unroll
  for (int r = 0; r < 4; ++r) {
    const int b = w * 16 + fq * 4 + r;
    acc[r] += P[((size_t)b * 21 + t) * 2048 + grow];
  }

  // gather 4 gates to lanes with fr<4 and apply elementwise
#pragma unroll
  for (int r = 0; r < 4; ++r) {
    const float x  = acc[r];
    const float xf = __shfl_xor(x, 4);
    const float xg = __shfl_xor(x, 8);
    const float xo = __shfl_xor(x, 12);
    if (fr < 4) {
      const int b = w * 16 + fq * 4 + r;
      const int u = u0 + fr;
      const size_t bu = (size_t)b * 512 + u;
      const float si = sigmoidf_(x);
      const float sf = sigmoidf_(xf);
      const float tg = tanhf(xg);
      const float so = sigmoidf_(xo);
      const float cn = sf * c[bu] + si * tg;
      c[bu] = cn;
      const float hn = so * tanhf(cn);
      h_out[bu] = (f16)hn;
      if (t >= 1)
        hs16[((size_t)b * T_DIM + (t - 1)) * 512 + u] = (f16)hn;
    }
  }
}

// ---------------------------------------------------------------------------
// Row softmax over V=32000, row staged in REGISTERS (1024 thr x 8 float4).
// No big LDS block -> multi-block/CU occupancy (vs 1 block/CU LDS version).
// exp stored back into regs in pass 2; pass 3 is multiply+store.
// One block per row. In-place safe: all reads precede all writes per block.
// ---------------------------------------------------------------------------
__device__ __forceinline__ float waveMax(float v) {
#pragma unroll
  for (int o = 32; o > 0; o >>= 1) v = fmaxf(v, __shfl_down(v, o));
  return v;
}
__device__ __forceinline__ float waveSum(float v) {
#pragma unroll
  for (int o = 32; o > 0; o >>= 1) v += __shfl_down(v, o);
  return v;
}

__global__ __launch_bounds__(1024) void softmax_reg_kernel(
    float* __restrict__ out) {
  float4* p4 = (float4*)(out + (size_t)blockIdx.x * V_DIM);
  const int t = threadIdx.x;
  __shared__ float sred[16];

  float4 v[8];
  // pass 1: load + max (chunk j at i = j*1024 + t; only j=7 partially masked)
  float m = -1e30f;
#pragma unroll
  for (int j = 0; j < 8; ++j) {
    const int i = j * 1024 + t;
    if (i < 8000) {
      v[j] = p4[i];
      m = fmaxf(m, fmaxf(fmaxf(v[j].x, v[j].y), fmaxf(v[j].z, v[j].w)));
    }
  }
  m = waveMax(m);
  if ((t & 63) == 0) sred[t >> 6] = m;
  __syncthreads();
  float mb = sred[0];
#pragma unroll
  for (int k = 1; k < 16; ++k) mb = fmaxf(mb, sred[k]);
  __syncthreads();

  // pass 2: exp into regs + sum
  float s = 0.f;
#pragma unroll
  for (int j = 0; j < 8; ++j) {
    const int i = j * 1024 + t;
    if (i < 8000) {
      v[j].x = expf(v[j].x - mb);
      v[j].y = expf(v[j].y - mb);
      v[j].z = expf(v[j].z - mb);
      v[j].w = expf(v[j].w - mb);
      s += v[j].x + v[j].y + v[j].z + v[j].w;
    }
  }
  s = waveSum(s);
  if ((t & 63) == 0) sred[t >> 6] = s;
  __syncthreads();
  float sb = sred[0];
#pragma unroll
  for (int k = 1; k < 16; ++k) sb += sred[k];
  const float inv = 1.0f / sb;

  // pass 3: scale + store
#pragma unroll
  for (int j = 0; j < 8; ++j) {
    const int i = j * 1024 + t;
    if (i < 8000) {
      float4 o;
      o.x = v[j].x * inv;
      o.y = v[j].y * inv;
      o.z = v[j].z * inv;
      o.w = v[j].w * inv;
      p4[i] = o;
    }
  }
}

// ---------------------------------------------------------------------------
extern "C" void kernel_launch(void* const* d_in, const int* in_sizes, int n_in,
                              void* d_out, int out_size, void* d_ws, size_t ws_size,
                              hipStream_t stream) {
  const float* features = (const float*)d_in[0];
  const int*   captions = (const int*)d_in[1];
  // d_in[2] = lenghts (unused by the reference)
  const float* emb      = (const float*)d_in[3];
  const float* w_ih     = (const float*)d_in[4];
  const float* w_hh     = (const float*)d_in[5];
  const float* b_ih     = (const float*)d_in[6];
  const float* b_hh     = (const float*)d_in[7];
  const float* fc_w     = (const float*)d_in[8];
  const float* fc_b     = (const float*)d_in[9];
  float* out = (float*)d_out;

  // ---- persistent-ish scratch in d_ws (proven budget <= 32.9MB) ----
  char* ws = (char*)d_ws;
  float* c    = (float*)ws; ws += (size_t)B_DIM * H_DIM * 4;            // 128 KB
  f16*   hs16 = (f16*)ws;  ws += (size_t)B_DIM * T_DIM * H_DIM * 2;     // 1.25 MB
  f16*   w16  = (f16*)ws;  ws += (size_t)V_DIM * H_DIM * 2;             // 31.25 MB

  // ---- transient scratch carved from d_out (all dead before fc_gemm) ----
  // float offsets; every region 16B-aligned, all <= 19.3MB < 163.8MB.
  float* P     = out;                          // [1408][2048] f32, 11.5 MB
  f16*   x16   = (f16*)(out + 3000000);        // [1408][512] f16, 1.44 MB
  f16*   wih16 = (f16*)(out + 3400000);        // [2048][512] f16, 2 MB
  f16*   whh16 = (f16*)(out + 4000000);        // [2048][512] f16, 2 MB
  float* bsum  = out + 4600000;                // [2048] f32
  f16*   h16a  = (f16*)(out + 4700000);        // [64][512] f16, 64 KB
  f16*   h16b  = (f16*)(out + 4800000);        // [64][512] f16, 64 KB

  hipMemsetAsync(c,    0, (size_t)B_DIM * H_DIM * 4, stream);
  hipMemsetAsync(h16a, 0, (size_t)B_DIM * H_DIM * 2, stream);

  gather_x16_kernel<<<1408, 128, 0, stream>>>(features, captions, emb, x16);
  convert_w_kernel<<<1024, 256, 0, stream>>>(w_ih, wih16);    // 2048*512
  convert_w_kernel<<<1024, 256, 0, stream>>>(w_hh, whh16);    // 2048*512
  convert_w_kernel<<<16000, 256, 0, stream>>>(fc_w, w16);     // 32000*512
  bias_sum_kernel<<<8, 256, 0, stream>>>(b_ih, b_hh, bsum);

  // proj: P[1408][2048] = x16 @ wih16^T + bsum
  gemm16_kernel<<<dim3(16, 11), 256, 0, stream>>>(x16, wih16, bsum, P, 2048);

  f16* hb[2] = {h16a, h16b};
  for (int t = 0; t <= T_DIM; ++t) {
    lstm_mfma_step<<<128, 256, 0, stream>>>(P, whh16, hb[t & 1],
                                            hb[(t + 1) & 1], c, hs16, t);
  }

  // fc: out[1280][32000] = hs16 @ w16^T + fc_b
  gemm16_kernel<<<dim3(250, 10), 256, 0, stream>>>(hs16, w16, fc_b, out, 32000);
  softmax_reg_kernel<<<1280, 1024, 0, stream>>>(out);
}